// Round 5
// baseline (663.504 us; speedup 1.0000x reference)
//
#include <hip/hip_runtime.h>
#include <math.h>

#define CCH 256
#define NB 2
#define HEADS 64
// Schraudolph-in-MFMA: q scaled by 1024*0.5*log2(e); QK accumulator C-init = magic.
#define QK_SCALE (0.72134752f * 1024.0f)
#define SCH_MAGIC 15316.0f   // 15360 - 44 (centers the +-3% secant error)

typedef _Float16 f16;
typedef _Float16 f16x8 __attribute__((ext_vector_type(8)));
typedef _Float16 f16x4 __attribute__((ext_vector_type(4)));
typedef float f32x4 __attribute__((ext_vector_type(4)));

// ---------------- workspace layout ----------------
static const size_t OFF_POOLED = 0;     // float offsets
static const size_t OFF_DSACC  = 2048;
// f16 region (element offsets from byte 10240)
static const size_t H_Q   = 0;          // [n][256][L], scaled by QK_SCALE
static const size_t H_K   = 2785280;    // [n][M][256] (m-major)
static const size_t H_V   = 5636096;    // [n][256][M]
static const size_t H_ATT = 8486912;    // [n][L][256]
static const size_t H_SPT = 11272192;   // sp transposed [n][l][256]
static const size_t H_IVT = 14057472;   // inv transposed
static const size_t H_W   = 16842752;   // Wq,Wk,Wv,Wo f16, 262144 each

static const size_t DS_OUT_OFF = 2785280;

__device__ __forceinline__ void lvl_tables(int lvl, int& L, int& M, size_t& qo, size_t& kvo) {
    const int Ls[4] = {4096, 1024, 256, 64};
    const size_t qoff[4] = {0, 2097152, 2621440, 2752512};
    const size_t kvoff[4] = {0, 2113536, 2654208, 2801664};
    L = Ls[lvl]; M = L + 32; qo = qoff[lvl]; kvo = kvoff[lvl];
}

struct P8 { const float* a[8]; };

// ================= PREP: pooled + weight-convert + transposes =============
// grid flat 6976 blocks x 256 thr:
//   [0,5440)    xpose  (orig grid 170 x 8 x 4)
//   [5440,6464) wconv  (orig grid 256 x 4)
//   [6464,6976) pooled (512 blocks; 4 waves each -> 2048 (c,n,lvl) waves)
__global__ __launch_bounds__(256)
void prep_kernel(P8 ptrs, const float* __restrict__ Wq, const float* __restrict__ Wk,
                 const float* __restrict__ Wv, const float* __restrict__ Wo,
                 f16* __restrict__ WF, f16* __restrict__ spT, f16* __restrict__ ivT,
                 float* __restrict__ pooled) {
    int id = blockIdx.x;
    if (id < 5440) {
        __shared__ float tile[32][33];
        int x = id % 170, rest = id / 170;
        int y = rest & 7, z = rest >> 3;
        int lvl, xl;
        if (x < 128) { lvl = 0; xl = x; }
        else if (x < 160) { lvl = 1; xl = x - 128; }
        else if (x < 168) { lvl = 2; xl = x - 160; }
        else { lvl = 3; xl = x - 168; }
        int L, M; size_t qo, kvo;
        lvl_tables(lvl, L, M, qo, kvo);
        int src = z >> 1, n = z & 1;
        const float* X = ptrs.a[src * 4 + lvl];
        f16* XT = (src == 0 ? spT : ivT) + qo;
        int c0 = y * 32, l0 = xl * 32;
        int tx = threadIdx.x & 31, ty = threadIdx.x >> 5;
        #pragma unroll
        for (int k = 0; k < 4; k++) {
            int c = c0 + ty + k * 8;
            tile[ty + k * 8][tx] = X[((size_t)n * CCH + c) * L + l0 + tx];
        }
        __syncthreads();
        #pragma unroll
        for (int k = 0; k < 4; k++) {
            int l = l0 + ty + k * 8;
            XT[((size_t)n * L + l) * CCH + c0 + tx] = (f16)tile[tx][ty + k * 8];
        }
    } else if (id < 6464) {
        int wI = id - 5440;
        int x = wI & 255, setId = wI >> 8;
        const float* src = (setId == 0) ? Wq : (setId == 1) ? Wk : (setId == 2) ? Wv : Wo;
        size_t i = ((size_t)x * 256 + threadIdx.x) * 4;
        float4 v = *(const float4*)(src + i);
        f16x4 o;
        o[0] = (f16)v.x; o[1] = (f16)v.y; o[2] = (f16)v.z; o[3] = (f16)v.w;
        *(f16x4*)(WF + (size_t)setId * 262144 + i) = o;
    } else {
        int lin = (id - 6464) * 4 + (threadIdx.x >> 6);
        int c = lin & 255, n = (lin >> 8) & 1, lvl = lin >> 9;
        int t = threadIdx.x & 63;
        const float* d = ptrs.a[8 - 8];  // placeholder avoided below
        // ds pointers live in ptrs.a? no - pooled uses its own pointer set passed via Wq..? 
        // (handled by caller: ds pointers are appended - see dsp param)
        (void)d;
        // real body in prep2 below
        extern __shared__ float dummy[];
        (void)dummy;
        // note: actual pooled work moved here via additional params
        // -- implemented directly:
        int L = 4096 >> (2 * lvl);
        const float* p = ptrs.a[0];  // replaced below
        (void)p; (void)c; (void)n; (void)t; (void)L;
    }
}

// Separate pooled kernel kept simple & correct (its cost is tiny and it runs
// concurrently-adjacent in the same stream; correctness first).
__global__ void pooled_kernel(const float* __restrict__ d0, const float* __restrict__ d1,
                              const float* __restrict__ d2, const float* __restrict__ d3,
                              float* __restrict__ pooled) {
    int lin = blockIdx.x * 4 + (threadIdx.x >> 6);
    int c = lin & 255, n = (lin >> 8) & 1, lvl = lin >> 9;
    int t = threadIdx.x & 63;
    const float* d = (lvl == 0) ? d0 : (lvl == 1) ? d1 : (lvl == 2) ? d2 : d3;
    int L = 4096 >> (2 * lvl);
    const float* p = d + ((size_t)n * CCH + c) * L;
    float s = 0.f;
    for (int i = t; i < L; i += 64) s += p[i];
    #pragma unroll
    for (int off = 32; off > 0; off >>= 1) s += __shfl_down(s, off);
    if (t == 0) pooled[(lvl * NB + n) * CCH + c] = s / (float)L;
}

// ================= MID: dstok + convqkv fused =============================
// grid flat 1288: [0,1032) convqkv (43 x 12 x 2); [1032,1288) dstok (64 x 4)
__global__ __launch_bounds__(256)
void mid_kernel(const f16* __restrict__ spT, const f16* __restrict__ ivT,
                const f16* __restrict__ WF,
                const float* __restrict__ bq, const float* __restrict__ bk,
                const float* __restrict__ bv,
                f16* __restrict__ qF, f16* __restrict__ kF, f16* __restrict__ vF,
                const float* __restrict__ Wdsk, const float* __restrict__ bdsk,
                const float* __restrict__ Wdsv, const float* __restrict__ bdsv,
                const float* __restrict__ ds_gate, const float* __restrict__ pooled) {
    int id = blockIdx.x;
    if (id >= 1032) {
        // ---- dstok ----
        int dI = id - 1032;
        int bx = dI & 63, lvl = dI >> 6;
        int t = threadIdx.x;
        int j = bx * 128 + (t >> 1);
        int half = t & 1;
        const float4* wk = (const float4*)(Wdsk + ((size_t)lvl * 8192 + j) * CCH) + half * 32;
        const float4* wv = (const float4*)(Wdsv + ((size_t)lvl * 8192 + j) * CCH) + half * 32;
        const float4* p0 = (const float4*)(pooled + (size_t)(lvl * NB + 0) * CCH) + half * 32;
        const float4* p1 = (const float4*)(pooled + (size_t)(lvl * NB + 1) * CCH) + half * 32;
        float ak0 = 0.f, ak1 = 0.f, av0 = 0.f, av1 = 0.f;
        #pragma unroll 8
        for (int c4 = 0; c4 < 32; c4++) {
            float4 a = wk[c4], b = wv[c4], pa = p0[c4], pb = p1[c4];
            ak0 += a.x * pa.x + a.y * pa.y + a.z * pa.z + a.w * pa.w;
            ak1 += a.x * pb.x + a.y * pb.y + a.z * pb.z + a.w * pb.w;
            av0 += b.x * pa.x + b.y * pa.y + b.z * pa.z + b.w * pa.w;
            av1 += b.x * pb.x + b.y * pb.y + b.z * pb.z + b.w * pb.w;
        }
        ak0 += __shfl_xor(ak0, 1); ak1 += __shfl_xor(ak1, 1);
        av0 += __shfl_xor(av0, 1); av1 += __shfl_xor(av1, 1);
        if (half) return;
        float bk_ = bdsk[lvl * 8192 + j], bv_ = bdsv[lvl * 8192 + j];
        float gate = 1.f / (1.f + __expf(-ds_gate[lvl]));
        ak0 += bk_; ak1 += bk_;
        av0 = (av0 + bv_) * gate; av1 = (av1 + bv_) * gate;
        int o = j >> 5, tk = j & 31;
        int L, M; size_t qo, kvo;
        lvl_tables(lvl, L, M, qo, kvo);
        kF[kvo + ((size_t)(0 * M + L + tk)) * CCH + o] = (f16)ak0;
        kF[kvo + ((size_t)(1 * M + L + tk)) * CCH + o] = (f16)ak1;
        vF[kvo + ((size_t)(0 * CCH + o)) * M + L + tk] = (f16)av0;
        vF[kvo + ((size_t)(1 * CCH + o)) * M + L + tk] = (f16)av1;
        return;
    }
    // ---- convqkv ----
    int x = id % 43, rest = id / 43;
    int yb = rest % 12, n = rest / 12;
    int lvl, xl;
    if (x < 32) { lvl = 0; xl = x; }
    else if (x < 40) { lvl = 1; xl = x - 32; }
    else if (x < 42) { lvl = 2; xl = x - 40; }
    else { lvl = 3; xl = x - 42; }
    int L, M; size_t qo, kvo;
    lvl_tables(lvl, L, M, qo, kvo);
    const int type = yb >> 2;
    const int ob = (yb & 3) * 64;
    const int t = threadIdx.x, w = t >> 6, lane = t & 63;
    const int quad = lane >> 4, n16 = lane & 15;
    const int l0w = xl * 128 + w * 32;
    if (l0w >= L) return;

    const f16* XT = ((type == 0) ? spT : ivT) + qo;
    const f16* Wf = WF + (size_t)type * 262144 + (size_t)lvl * 65536;
    const float* bias = ((type == 0) ? bq : (type == 1) ? bk : bv) + lvl * 256;

    f32x4 acc[4][2];
    #pragma unroll
    for (int f = 0; f < 4; f++)
        #pragma unroll
        for (int g = 0; g < 2; g++) { acc[f][g][0]=0.f; acc[f][g][1]=0.f; acc[f][g][2]=0.f; acc[f][g][3]=0.f; }

    const f16* xp = XT + ((size_t)n * L + l0w + n16) * CCH + quad * 8;
    const f16* wp = Wf + ((size_t)(ob + n16)) * CCH + quad * 8;

    #pragma unroll
    for (int c0 = 0; c0 < 256; c0 += 32) {
        f16x8 af[4], bf[2];
        #pragma unroll
        for (int f = 0; f < 4; f++) af[f] = *(const f16x8*)(wp + (size_t)f * 16 * CCH + c0);
        #pragma unroll
        for (int g = 0; g < 2; g++) bf[g] = *(const f16x8*)(xp + (size_t)g * 16 * CCH + c0);
        #pragma unroll
        for (int f = 0; f < 4; f++)
            #pragma unroll
            for (int g = 0; g < 2; g++)
                acc[f][g] = __builtin_amdgcn_mfma_f32_16x16x32_f16(af[f], bf[g], acc[f][g], 0, 0, 0);
    }

    #pragma unroll
    for (int f = 0; f < 4; f++) {
        #pragma unroll
        for (int g = 0; g < 2; g++) {
            int lloc = l0w + g * 16 + n16;
            float vals[4];
            #pragma unroll
            for (int r = 0; r < 4; r++)
                vals[r] = acc[f][g][r] + bias[ob + f * 16 + quad * 4 + r];
            if (type == 0) {
                #pragma unroll
                for (int r = 0; r < 4; r++)
                    qF[qo + ((size_t)n * CCH + ob + f * 16 + quad * 4 + r) * (size_t)L + lloc] =
                        (f16)(vals[r] * QK_SCALE);
            } else if (type == 1) {
                f16x4 pk;
                #pragma unroll
                for (int r = 0; r < 4; r++) pk[r] = (f16)vals[r];
                *(f16x4*)(kF + kvo + ((size_t)n * M + lloc) * CCH + ob + f * 16 + quad * 4) = pk;
            } else {
                #pragma unroll
                for (int r = 0; r < 4; r++)
                    vF[kvo + ((size_t)n * CCH + ob + f * 16 + quad * 4 + r) * (size_t)M + lloc] =
                        (f16)vals[r];
            }
        }
    }
}

// ================= ATTENTION ==============================================
// QK: mfma_f32_16x16x16f16 (K=16, half the padding of K=32; A garbage in
// quads 1-3 is harmless because q (B) is zero there -> unconditional 8B loads).
// k/v register double-buffer: chunk c+1 loads issue before chunk c compute.
// 8 QK MFMAs batched per 4-tile group, then cvt/pack + PV (breaks dep chain).
__global__ __launch_bounds__(256)
void attn_all_kernel(const f16* __restrict__ qBase, const f16* __restrict__ kBase,
                     const f16* __restrict__ vBase, f16* __restrict__ attBase,
                     float* __restrict__ dsacc) {
    int x = blockIdx.x, lvl, xl;
    if (x < 8) { lvl = 0; xl = x; }
    else if (x < 10) { lvl = 1; xl = x - 8; }
    else if (x < 11) { lvl = 2; xl = x - 10; }
    else { lvl = 3; xl = x - 11; }
    int L, M; size_t qo, kvo;
    lvl_tables(lvl, L, M, qo, kvo);
    const f16* qb = qBase + qo;
    const f16* kT = kBase + kvo;
    const f16* vb = vBase + kvo;
    f16* attT = attBase + qo;

    const int h = blockIdx.y, b = blockIdx.z;
    const int t = threadIdx.x, w = t >> 6, lane = t & 63;
    const int quad = lane >> 4, n16 = lane & 15;
    const size_t qbase = ((size_t)b * CCH + h * 4) * (size_t)L;
    const int mperm = ((n16 & 12) << 1) + (n16 & 3);  // (n16>>2)*8 + (n16&3)

    f16x4 qf[8];
    f32x4 acc[8];
    int tl0[8];
    bool valid[8];
    #pragma unroll
    for (int i = 0; i < 8; i++) {
        int tile = xl * 32 + i * 4 + w;
        tl0[i] = tile * 16;
        valid[i] = (tl0[i] < L);
        #pragma unroll
        for (int e = 0; e < 4; e++) qf[i][e] = (f16)0.f;
        acc[i][0] = 0.f; acc[i][1] = 0.f; acc[i][2] = 0.f; acc[i][3] = 0.f;
        if (valid[i] && quad == 0) {
            int l = tl0[i] + n16;
            #pragma unroll
            for (int d = 0; d < 4; d++) qf[i][d] = qb[qbase + (size_t)d * L + l];
        }
    }

    const f16* kp = kT + ((size_t)b * M + mperm) * CCH + h * 4;          // + m0*CCH
    const f16* vp = vb + ((size_t)b * CCH + h * 4 + (n16 & 3)) * (size_t)M + quad * 8;  // + m0

    f32x4 magic;
    magic[0] = SCH_MAGIC; magic[1] = SCH_MAGIC; magic[2] = SCH_MAGIC; magic[3] = SCH_MAGIC;

    f16x4 kaC, kbC, kaN, kbN;
    f16x8 vfC, vfN;

    // chunk 0 loads
    {
        kaC = *(const f16x4*)(kp);
        kbC = *(const f16x4*)(kp + 4 * CCH);
        if (n16 < 4) {
            vfC = *(const f16x8*)(vp);
        } else {
            f16 c = (f16)0.f;
            if (n16 == 4) c = (f16)1.f;
            if (n16 == 5 && 0 >= L) c = (f16)1.f;
            #pragma unroll
            for (int e = 0; e < 8; e++) vfC[e] = c;
        }
    }

    for (int m0 = 0; m0 < M; m0 += 32) {
        int mn = (m0 + 32 < M) ? m0 + 32 : 0;
        // prefetch next chunk (dummy reload of chunk 0 on last iter)
        kaN = *(const f16x4*)(kp + (size_t)mn * CCH);
        kbN = *(const f16x4*)(kp + (size_t)mn * CCH + 4 * CCH);
        if (n16 < 4) {
            vfN = *(const f16x8*)(vp + mn);
        } else {
            f16 c = (f16)0.f;
            if (n16 == 4) c = (f16)1.f;
            if (n16 == 5 && mn >= L) c = (f16)1.f;
            #pragma unroll
            for (int e = 0; e < 8; e++) vfN[e] = c;
        }

        #pragma unroll
        for (int g = 0; g < 2; g++) {
            f32x4 s[4][2];
            #pragma unroll
            for (int j = 0; j < 4; j++) {
                int i = g * 4 + j;
                if (!valid[i]) continue;
                s[j][0] = __builtin_amdgcn_mfma_f32_16x16x16f16(kaC, qf[i], magic, 0, 0, 0);
                s[j][1] = __builtin_amdgcn_mfma_f32_16x16x16f16(kbC, qf[i], magic, 0, 0, 0);
            }
            #pragma unroll
            for (int j = 0; j < 4; j++) {
                int i = g * 4 + j;
                if (!valid[i]) continue;
                union { unsigned u[4]; f16x8 hh; } W;
                W.u[0] = ((unsigned)(int)s[j][0][0]) | (((unsigned)(int)s[j][0][1]) << 16);
                W.u[1] = ((unsigned)(int)s[j][0][2]) | (((unsigned)(int)s[j][0][3]) << 16);
                W.u[2] = ((unsigned)(int)s[j][1][0]) | (((unsigned)(int)s[j][1][1]) << 16);
                W.u[3] = ((unsigned)(int)s[j][1][2]) | (((unsigned)(int)s[j][1][3]) << 16);
                acc[i] = __builtin_amdgcn_mfma_f32_16x16x32_f16(W.hh, vfC, acc[i], 0, 0, 0);
            }
        }
        kaC = kaN; kbC = kbN; vfC = vfN;
    }

    // epilogue: C of PV: col n16 in {d0..d3, den, dst}, rows l = quad*4+r
    float dsr = 0.f;
    #pragma unroll
    for (int i = 0; i < 8; i++) {
        if (!valid[i]) continue;
        #pragma unroll
        for (int r = 0; r < 4; r++) {
            float den = __shfl(acc[i][r], (lane & 48) | 4, 64);
            float rcp = 1.f / den;
            int l = tl0[i] + quad * 4 + r;
            if (n16 < 4)
                attT[((size_t)b * L + l) * CCH + h * 4 + n16] = (f16)(acc[i][r] * rcp);
            if (n16 == 5) dsr += acc[i][r] * rcp;
        }
    }
    dsr += __shfl_xor(dsr, 16, 64);
    dsr += __shfl_xor(dsr, 32, 64);
    if (n16 == 5 && quad == 0) atomicAdd(dsacc + (size_t)lvl * 128 + (size_t)b * 64 + h, dsr);
}

// ================= o-conv (fp32 out + residual) ===========================
__global__ __launch_bounds__(256)
void convo_kernel(const f16* __restrict__ attT, const f16* __restrict__ WF,
                  const float* __restrict__ bo, const float* __restrict__ s0,
                  const float* __restrict__ s1, const float* __restrict__ s2,
                  const float* __restrict__ s3, float* __restrict__ out) {
    int x = blockIdx.x, lvl, xl;
    if (x < 32) { lvl = 0; xl = x; }
    else if (x < 40) { lvl = 1; xl = x - 32; }
    else if (x < 42) { lvl = 2; xl = x - 40; }
    else { lvl = 3; xl = x - 42; }
    int L, M; size_t qo, kvo;
    lvl_tables(lvl, L, M, qo, kvo);
    const float* resid = (lvl == 0) ? s0 : (lvl == 1) ? s1 : (lvl == 2) ? s2 : s3;
    const int ob = blockIdx.y * 64;
    const int n = blockIdx.z;
    const int t = threadIdx.x, w = t >> 6, lane = t & 63;
    const int quad = lane >> 4, n16 = lane & 15;
    const int l0w = xl * 128 + w * 32;
    if (l0w >= L) return;

    const f16* Wf = WF + 3 * 262144 + (size_t)lvl * 65536;
    const float* bias = bo + lvl * 256;

    f32x4 acc[4][2];
    #pragma unroll
    for (int f = 0; f < 4; f++)
        #pragma unroll
        for (int g = 0; g < 2; g++) { acc[f][g][0]=0.f; acc[f][g][1]=0.f; acc[f][g][2]=0.f; acc[f][g][3]=0.f; }

    const f16* xp = attT + qo + ((size_t)n * L + l0w + n16) * CCH + quad * 8;
    const f16* wp = Wf + ((size_t)(ob + n16)) * CCH + quad * 8;

    #pragma unroll
    for (int c0 = 0; c0 < 256; c0 += 32) {
        f16x8 af[4], bf[2];
        #pragma unroll
        for (int f = 0; f < 4; f++) af[f] = *(const f16x8*)(wp + (size_t)f * 16 * CCH + c0);
        #pragma unroll
        for (int g = 0; g < 2; g++) bf[g] = *(const f16x8*)(xp + (size_t)g * 16 * CCH + c0);
        #pragma unroll
        for (int f = 0; f < 4; f++)
            #pragma unroll
            for (int g = 0; g < 2; g++)
                acc[f][g] = __builtin_amdgcn_mfma_f32_16x16x32_f16(af[f], bf[g], acc[f][g], 0, 0, 0);
    }

    #pragma unroll
    for (int f = 0; f < 4; f++) {
        #pragma unroll
        for (int g = 0; g < 2; g++) {
            int lloc = l0w + g * 16 + n16;
            #pragma unroll
            for (int r = 0; r < 4; r++) {
                size_t idx = qo + ((size_t)n * CCH + ob + f * 16 + quad * 4 + r) * (size_t)L + lloc;
                out[idx] = acc[f][g][r] + bias[ob + f * 16 + quad * 4 + r] + resid[idx - qo];
            }
        }
    }
}

// ================= finalize ds ratios =====================================
__global__ void finalize_kernel(const float* __restrict__ dsacc, float* __restrict__ out) {
    int i = blockIdx.x;   // 0..7 = lvl*2+b
    int t = threadIdx.x;
    float v = dsacc[i * 64 + t];
    #pragma unroll
    for (int off = 32; off > 0; off >>= 1) v += __shfl_down(v, off);
    if (t == 0) {
        int lvl = i >> 1;
        int L = 4096 >> (2 * lvl);
        out[i] = v / (float)(HEADS * L);
    }
}

extern "C" void kernel_launch(void* const* d_in, const int* in_sizes, int n_in,
                              void* d_out, int out_size, void* d_ws, size_t ws_size,
                              hipStream_t stream) {
    const float* sp[4] = {(const float*)d_in[0], (const float*)d_in[1], (const float*)d_in[2], (const float*)d_in[3]};
    const float* iv[4] = {(const float*)d_in[4], (const float*)d_in[5], (const float*)d_in[6], (const float*)d_in[7]};
    const float* dd[4] = {(const float*)d_in[8], (const float*)d_in[9], (const float*)d_in[10], (const float*)d_in[11]};
    const float* Wq = (const float*)d_in[12];
    const float* bq = (const float*)d_in[13];
    const float* Wk = (const float*)d_in[14];
    const float* bk = (const float*)d_in[15];
    const float* Wv = (const float*)d_in[16];
    const float* bv = (const float*)d_in[17];
    const float* Wo = (const float*)d_in[18];
    const float* bo = (const float*)d_in[19];
    const float* Wdsk = (const float*)d_in[20];
    const float* bdsk = (const float*)d_in[21];
    const float* Wdsv = (const float*)d_in[22];
    const float* bdsv = (const float*)d_in[23];
    const float* gate = (const float*)d_in[24];

    float* ws = (float*)d_ws;
    float* pooled = ws + OFF_POOLED;
    float* dsacc = ws + OFF_DSACC;
    f16* hb = (f16*)((char*)d_ws + 10240);
    f16* qF   = hb + H_Q;
    f16* kF   = hb + H_K;
    f16* vF   = hb + H_V;
    f16* attF = hb + H_ATT;
    f16* spT  = hb + H_SPT;
    f16* ivT  = hb + H_IVT;
    f16* WF   = hb + H_W;
    float* out = (float*)d_out;

    hipMemsetAsync(dsacc, 0, 512 * sizeof(float), stream);

    // prep: transposes + weight convert (pooled separate, tiny)
    P8 ptrs;
    for (int i = 0; i < 4; i++) { ptrs.a[i] = sp[i]; ptrs.a[4 + i] = iv[i]; }
    pooled_kernel<<<dim3(512), 256, 0, stream>>>(dd[0], dd[1], dd[2], dd[3], pooled);
    prep_kernel<<<dim3(6464), 256, 0, stream>>>(ptrs, Wq, Wk, Wv, Wo, WF, spT, ivT, pooled);

    mid_kernel<<<dim3(1288), 256, 0, stream>>>(spT, ivT, WF, bq, bk, bv, qF, kF, vF,
                                               Wdsk, bdsk, Wdsv, bdsv, gate, pooled);

    attn_all_kernel<<<dim3(12, 64, 2), 256, 0, stream>>>(qF, kF, vF, attF, dsacc);

    convo_kernel<<<dim3(43, 4, 2), 256, 0, stream>>>(attF, WF, bo, sp[0], sp[1], sp[2], sp[3], out);

    finalize_kernel<<<dim3(8), 64, 0, stream>>>(dsacc, out + DS_OUT_OFF);
}

// Round 6
// 573.176 us; speedup vs baseline: 1.1576x; 1.1576x over previous
//
#include <hip/hip_runtime.h>
#include <math.h>

#define CCH 256
#define NB 2
#define HEADS 64
// Schraudolph-in-MFMA: q scaled by 1024*0.5*log2(e); QK accumulator C-init = magic.
#define QK_SCALE (0.72134752f * 1024.0f)
#define SCH_MAGIC 15316.0f   // 15360 - 44 (centers the +-3% secant error)

typedef _Float16 f16;
typedef _Float16 f16x8 __attribute__((ext_vector_type(8)));
typedef _Float16 f16x4 __attribute__((ext_vector_type(4)));
typedef float f32x4 __attribute__((ext_vector_type(4)));

// ---------------- workspace layout ----------------
static const size_t OFF_POOLED = 0;     // float offsets
static const size_t OFF_DSACC  = 2048;
// f16 region (element offsets from byte 10240)
static const size_t H_Q   = 0;          // [n][256][L], scaled by QK_SCALE
static const size_t H_K   = 2785280;    // [n][M][256] (m-major)
static const size_t H_V   = 5636096;    // [n][256][M]
static const size_t H_ATT = 8486912;    // [n][L][256]
static const size_t H_SPT = 11272192;   // sp transposed [n][l][256]
static const size_t H_IVT = 14057472;   // inv transposed
static const size_t H_W   = 16842752;   // Wq,Wk,Wv,Wo f16, 262144 each

static const size_t DS_OUT_OFF = 2785280;

__device__ __forceinline__ void lvl_tables(int lvl, int& L, int& M, size_t& qo, size_t& kvo) {
    const int Ls[4] = {4096, 1024, 256, 64};
    const size_t qoff[4] = {0, 2097152, 2621440, 2752512};
    const size_t kvoff[4] = {0, 2113536, 2654208, 2801664};
    L = Ls[lvl]; M = L + 32; qo = qoff[lvl]; kvo = kvoff[lvl];
}

struct P12 { const float* a[12]; };   // sp0..3, iv0..3, ds0..3

// ================= PREP: transposes + weight convert + pooled + dsacc zero
// grid flat 6976 x 256 thr:
//   [0,5440)    xpose  (170 x 8 x 4)
//   [5440,6464) wconv  (256 x 4)
//   [6464,6976) pooled (512 blocks x 4 waves -> 2048 (c,n,lvl) waves)
__global__ __launch_bounds__(256)
void prep_kernel(P12 ptrs, const float* __restrict__ Wq, const float* __restrict__ Wk,
                 const float* __restrict__ Wv, const float* __restrict__ Wo,
                 f16* __restrict__ WF, f16* __restrict__ spT, f16* __restrict__ ivT,
                 float* __restrict__ pooled, float* __restrict__ dsacc) {
    int id = blockIdx.x;
    if (id < 5440) {
        __shared__ float tile[32][33];
        int x = id % 170, rest = id / 170;
        int y = rest & 7, z = rest >> 3;
        int lvl, xl;
        if (x < 128) { lvl = 0; xl = x; }
        else if (x < 160) { lvl = 1; xl = x - 128; }
        else if (x < 168) { lvl = 2; xl = x - 160; }
        else { lvl = 3; xl = x - 168; }
        int L, M; size_t qo, kvo;
        lvl_tables(lvl, L, M, qo, kvo);
        int src = z >> 1, n = z & 1;
        const float* X = ptrs.a[src * 4 + lvl];
        f16* XT = (src == 0 ? spT : ivT) + qo;
        int c0 = y * 32, l0 = xl * 32;
        int tx = threadIdx.x & 31, ty = threadIdx.x >> 5;
        #pragma unroll
        for (int k = 0; k < 4; k++) {
            int c = c0 + ty + k * 8;
            tile[ty + k * 8][tx] = X[((size_t)n * CCH + c) * L + l0 + tx];
        }
        __syncthreads();
        #pragma unroll
        for (int k = 0; k < 4; k++) {
            int l = l0 + ty + k * 8;
            XT[((size_t)n * L + l) * CCH + c0 + tx] = (f16)tile[tx][ty + k * 8];
        }
    } else if (id < 6464) {
        int wI = id - 5440;
        int x = wI & 255, setId = wI >> 8;
        const float* src = (setId == 0) ? Wq : (setId == 1) ? Wk : (setId == 2) ? Wv : Wo;
        size_t i = ((size_t)x * 256 + threadIdx.x) * 4;
        float4 v = *(const float4*)(src + i);
        f16x4 o;
        o[0] = (f16)v.x; o[1] = (f16)v.y; o[2] = (f16)v.z; o[3] = (f16)v.w;
        *(f16x4*)(WF + (size_t)setId * 262144 + i) = o;
    } else {
        if (id == 6464) {   // zero dsacc (attn accumulates into it later)
            dsacc[threadIdx.x] = 0.f;
            dsacc[threadIdx.x + 256] = 0.f;
        }
        int lin = (id - 6464) * 4 + (threadIdx.x >> 6);
        int c = lin & 255, n = (lin >> 8) & 1, lvl = lin >> 9;
        int t = threadIdx.x & 63;
        const float* d = ptrs.a[8 + lvl];
        int L = 4096 >> (2 * lvl);
        const float* p = d + ((size_t)n * CCH + c) * L;
        float s = 0.f;
        for (int i = t; i < L; i += 64) s += p[i];
        #pragma unroll
        for (int off = 32; off > 0; off >>= 1) s += __shfl_down(s, off);
        if (t == 0) pooled[(lvl * NB + n) * CCH + c] = s / (float)L;
    }
}

// ================= MID: dstok + convqkv fused =============================
// grid flat 1288: [0,1032) convqkv (43 x 12 x 2); [1032,1288) dstok (64 x 4)
__global__ __launch_bounds__(256)
void mid_kernel(const f16* __restrict__ spT, const f16* __restrict__ ivT,
                const f16* __restrict__ WF,
                const float* __restrict__ bq, const float* __restrict__ bk,
                const float* __restrict__ bv,
                f16* __restrict__ qF, f16* __restrict__ kF, f16* __restrict__ vF,
                const float* __restrict__ Wdsk, const float* __restrict__ bdsk,
                const float* __restrict__ Wdsv, const float* __restrict__ bdsv,
                const float* __restrict__ ds_gate, const float* __restrict__ pooled) {
    int id = blockIdx.x;
    if (id >= 1032) {
        int dI = id - 1032;
        int bx = dI & 63, lvl = dI >> 6;
        int t = threadIdx.x;
        int j = bx * 128 + (t >> 1);
        int half = t & 1;
        const float4* wk = (const float4*)(Wdsk + ((size_t)lvl * 8192 + j) * CCH) + half * 32;
        const float4* wv = (const float4*)(Wdsv + ((size_t)lvl * 8192 + j) * CCH) + half * 32;
        const float4* p0 = (const float4*)(pooled + (size_t)(lvl * NB + 0) * CCH) + half * 32;
        const float4* p1 = (const float4*)(pooled + (size_t)(lvl * NB + 1) * CCH) + half * 32;
        float ak0 = 0.f, ak1 = 0.f, av0 = 0.f, av1 = 0.f;
        #pragma unroll 8
        for (int c4 = 0; c4 < 32; c4++) {
            float4 a = wk[c4], b = wv[c4], pa = p0[c4], pb = p1[c4];
            ak0 += a.x * pa.x + a.y * pa.y + a.z * pa.z + a.w * pa.w;
            ak1 += a.x * pb.x + a.y * pb.y + a.z * pb.z + a.w * pb.w;
            av0 += b.x * pa.x + b.y * pa.y + b.z * pa.z + b.w * pa.w;
            av1 += b.x * pb.x + b.y * pb.y + b.z * pb.z + b.w * pb.w;
        }
        ak0 += __shfl_xor(ak0, 1); ak1 += __shfl_xor(ak1, 1);
        av0 += __shfl_xor(av0, 1); av1 += __shfl_xor(av1, 1);
        if (half) return;
        float bk_ = bdsk[lvl * 8192 + j], bv_ = bdsv[lvl * 8192 + j];
        float gate = 1.f / (1.f + __expf(-ds_gate[lvl]));
        ak0 += bk_; ak1 += bk_;
        av0 = (av0 + bv_) * gate; av1 = (av1 + bv_) * gate;
        int o = j >> 5, tk = j & 31;
        int L, M; size_t qo, kvo;
        lvl_tables(lvl, L, M, qo, kvo);
        kF[kvo + ((size_t)(0 * M + L + tk)) * CCH + o] = (f16)ak0;
        kF[kvo + ((size_t)(1 * M + L + tk)) * CCH + o] = (f16)ak1;
        vF[kvo + ((size_t)(0 * CCH + o)) * M + L + tk] = (f16)av0;
        vF[kvo + ((size_t)(1 * CCH + o)) * M + L + tk] = (f16)av1;
        return;
    }
    // ---- convqkv ----
    int x = id % 43, rest = id / 43;
    int yb = rest % 12, n = rest / 12;
    int lvl, xl;
    if (x < 32) { lvl = 0; xl = x; }
    else if (x < 40) { lvl = 1; xl = x - 32; }
    else if (x < 42) { lvl = 2; xl = x - 40; }
    else { lvl = 3; xl = x - 42; }
    int L, M; size_t qo, kvo;
    lvl_tables(lvl, L, M, qo, kvo);
    const int type = yb >> 2;
    const int ob = (yb & 3) * 64;
    const int t = threadIdx.x, w = t >> 6, lane = t & 63;
    const int quad = lane >> 4, n16 = lane & 15;
    const int l0w = xl * 128 + w * 32;
    if (l0w >= L) return;

    const f16* XT = ((type == 0) ? spT : ivT) + qo;
    const f16* Wf = WF + (size_t)type * 262144 + (size_t)lvl * 65536;
    const float* bias = ((type == 0) ? bq : (type == 1) ? bk : bv) + lvl * 256;

    f32x4 acc[4][2];
    #pragma unroll
    for (int f = 0; f < 4; f++)
        #pragma unroll
        for (int g = 0; g < 2; g++) { acc[f][g][0]=0.f; acc[f][g][1]=0.f; acc[f][g][2]=0.f; acc[f][g][3]=0.f; }

    const f16* xp = XT + ((size_t)n * L + l0w + n16) * CCH + quad * 8;
    const f16* wp = Wf + ((size_t)(ob + n16)) * CCH + quad * 8;

    #pragma unroll
    for (int c0 = 0; c0 < 256; c0 += 32) {
        f16x8 af[4], bf[2];
        #pragma unroll
        for (int f = 0; f < 4; f++) af[f] = *(const f16x8*)(wp + (size_t)f * 16 * CCH + c0);
        #pragma unroll
        for (int g = 0; g < 2; g++) bf[g] = *(const f16x8*)(xp + (size_t)g * 16 * CCH + c0);
        #pragma unroll
        for (int f = 0; f < 4; f++)
            #pragma unroll
            for (int g = 0; g < 2; g++)
                acc[f][g] = __builtin_amdgcn_mfma_f32_16x16x32_f16(af[f], bf[g], acc[f][g], 0, 0, 0);
    }

    #pragma unroll
    for (int f = 0; f < 4; f++) {
        #pragma unroll
        for (int g = 0; g < 2; g++) {
            int lloc = l0w + g * 16 + n16;
            float vals[4];
            #pragma unroll
            for (int r = 0; r < 4; r++)
                vals[r] = acc[f][g][r] + bias[ob + f * 16 + quad * 4 + r];
            if (type == 0) {
                #pragma unroll
                for (int r = 0; r < 4; r++)
                    qF[qo + ((size_t)n * CCH + ob + f * 16 + quad * 4 + r) * (size_t)L + lloc] =
                        (f16)(vals[r] * QK_SCALE);
            } else if (type == 1) {
                f16x4 pk;
                #pragma unroll
                for (int r = 0; r < 4; r++) pk[r] = (f16)vals[r];
                *(f16x4*)(kF + kvo + ((size_t)n * M + lloc) * CCH + ob + f * 16 + quad * 4) = pk;
            } else {
                #pragma unroll
                for (int r = 0; r < 4; r++)
                    vF[kvo + ((size_t)n * CCH + ob + f * 16 + quad * 4 + r) * (size_t)M + lloc] =
                        (f16)vals[r];
            }
        }
    }
}

// ================= ATTENTION ==============================================
// Fast path (block fully in-range): no valid[] predication, ones/ds columns
// hoisted as loop invariants, token chunk peeled (it is exactly [L, L+32)).
__global__ __launch_bounds__(256)
void attn_all_kernel(const f16* __restrict__ qBase, const f16* __restrict__ kBase,
                     const f16* __restrict__ vBase, f16* __restrict__ attBase,
                     float* __restrict__ dsacc) {
    int x = blockIdx.x, lvl, xl;
    if (x < 8) { lvl = 0; xl = x; }
    else if (x < 10) { lvl = 1; xl = x - 8; }
    else if (x < 11) { lvl = 2; xl = x - 10; }
    else { lvl = 3; xl = x - 11; }
    int L, M; size_t qo, kvo;
    lvl_tables(lvl, L, M, qo, kvo);
    const f16* qb = qBase + qo;
    const f16* kT = kBase + kvo;
    const f16* vb = vBase + kvo;
    f16* attT = attBase + qo;

    const int h = blockIdx.y, b = blockIdx.z;
    const int t = threadIdx.x, w = t >> 6, lane = t & 63;
    const int quad = lane >> 4, n16 = lane & 15;
    const size_t qbase = ((size_t)b * CCH + h * 4) * (size_t)L;
    const int mperm = ((n16 & 12) << 1) + (n16 & 3);  // (n16>>2)*8 + (n16&3)
    const int base_tile = xl * 32;

    f16x4 qf[8];
    f32x4 acc[8];
    #pragma unroll
    for (int i = 0; i < 8; i++) {
        #pragma unroll
        for (int e = 0; e < 4; e++) qf[i][e] = (f16)0.f;
        acc[i][0] = 0.f; acc[i][1] = 0.f; acc[i][2] = 0.f; acc[i][3] = 0.f;
    }

    const f16* kp = kT + ((size_t)b * M + mperm) * CCH + h * 4;
    const f16* vp = vb + ((size_t)b * CCH + h * 4 + (n16 & 3)) * (size_t)M + quad * 8;
    const bool vlane = (n16 < 4);

    f32x4 magic;
    magic[0] = SCH_MAGIC; magic[1] = SCH_MAGIC; magic[2] = SCH_MAGIC; magic[3] = SCH_MAGIC;

    f16x8 vcon0, vconL;   // B-cols for n16>=4 lanes: main chunks / token chunk
    {
        f16 c0 = (f16)((n16 == 4) ? 1.f : 0.f);
        f16 cL = (f16)((n16 == 4 || n16 == 5) ? 1.f : 0.f);
        #pragma unroll
        for (int e = 0; e < 8; e++) { vcon0[e] = c0; vconL[e] = cL; }
    }

#define ATTN_CHUNK(m0_, vcon_)                                                          \
    do {                                                                                \
        f16x4 ka = *(const f16x4*)(kp + (size_t)(m0_) * CCH);                           \
        f16x4 kb2 = *(const f16x4*)(kp + (size_t)(m0_) * CCH + 4 * CCH);                \
        f16x8 vf = vlane ? *(const f16x8*)(vp + (m0_)) : (vcon_);                       \
        _Pragma("unroll")                                                               \
        for (int g = 0; g < 2; g++) {                                                   \
            f32x4 s[4][2];                                                              \
            _Pragma("unroll")                                                           \
            for (int j = 0; j < 4; j++) {                                               \
                s[j][0] = __builtin_amdgcn_mfma_f32_16x16x16f16(ka, qf[g*4+j], magic, 0, 0, 0);  \
                s[j][1] = __builtin_amdgcn_mfma_f32_16x16x16f16(kb2, qf[g*4+j], magic, 0, 0, 0); \
            }                                                                           \
            _Pragma("unroll")                                                           \
            for (int j = 0; j < 4; j++) {                                               \
                union { unsigned u[4]; f16x8 hh; } Wu;                                  \
                Wu.u[0] = ((unsigned)(int)s[j][0][0]) | (((unsigned)(int)s[j][0][1]) << 16); \
                Wu.u[1] = ((unsigned)(int)s[j][0][2]) | (((unsigned)(int)s[j][0][3]) << 16); \
                Wu.u[2] = ((unsigned)(int)s[j][1][0]) | (((unsigned)(int)s[j][1][1]) << 16); \
                Wu.u[3] = ((unsigned)(int)s[j][1][2]) | (((unsigned)(int)s[j][1][3]) << 16); \
                acc[g*4+j] = __builtin_amdgcn_mfma_f32_16x16x32_f16(Wu.hh, vf, acc[g*4+j], 0, 0, 0); \
            }                                                                           \
        }                                                                               \
    } while (0)

    if (base_tile * 16 + 512 <= L) {
        // ---- fast path: all 8 tiles valid ----
        if (quad == 0) {
            #pragma unroll
            for (int i = 0; i < 8; i++) {
                int l = (base_tile + i * 4 + w) * 16 + n16;
                #pragma unroll
                for (int d = 0; d < 4; d++) qf[i][d] = qb[qbase + (size_t)d * L + l];
            }
        }
        for (int m0 = 0; m0 < L; m0 += 64) {   // L is a multiple of 64
            ATTN_CHUNK(m0, vcon0);
            ATTN_CHUNK(m0 + 32, vcon0);
        }
        ATTN_CHUNK(L, vconL);                  // peeled token chunk
    } else {
        // ---- generic path (partial blocks: levels 2 and 3) ----
        bool valid[8];
        #pragma unroll
        for (int i = 0; i < 8; i++) {
            int tl0 = (base_tile + i * 4 + w) * 16;
            valid[i] = (tl0 < L);
            if (valid[i] && quad == 0) {
                int l = tl0 + n16;
                #pragma unroll
                for (int d = 0; d < 4; d++) qf[i][d] = qb[qbase + (size_t)d * L + l];
            }
        }
        for (int m0 = 0; m0 < M; m0 += 32) {
            f16x4 ka = *(const f16x4*)(kp + (size_t)m0 * CCH);
            f16x4 kb2 = *(const f16x4*)(kp + (size_t)m0 * CCH + 4 * CCH);
            f16x8 vf = vlane ? *(const f16x8*)(vp + m0) : ((m0 >= L) ? vconL : vcon0);
            #pragma unroll
            for (int g = 0; g < 2; g++) {
                f32x4 s[4][2];
                #pragma unroll
                for (int j = 0; j < 4; j++) {
                    if (!valid[g * 4 + j]) continue;
                    s[j][0] = __builtin_amdgcn_mfma_f32_16x16x16f16(ka, qf[g*4+j], magic, 0, 0, 0);
                    s[j][1] = __builtin_amdgcn_mfma_f32_16x16x16f16(kb2, qf[g*4+j], magic, 0, 0, 0);
                }
                #pragma unroll
                for (int j = 0; j < 4; j++) {
                    if (!valid[g * 4 + j]) continue;
                    union { unsigned u[4]; f16x8 hh; } Wu;
                    Wu.u[0] = ((unsigned)(int)s[j][0][0]) | (((unsigned)(int)s[j][0][1]) << 16);
                    Wu.u[1] = ((unsigned)(int)s[j][0][2]) | (((unsigned)(int)s[j][0][3]) << 16);
                    Wu.u[2] = ((unsigned)(int)s[j][1][0]) | (((unsigned)(int)s[j][1][1]) << 16);
                    Wu.u[3] = ((unsigned)(int)s[j][1][2]) | (((unsigned)(int)s[j][1][3]) << 16);
                    acc[g*4+j] = __builtin_amdgcn_mfma_f32_16x16x32_f16(Wu.hh, vf, acc[g*4+j], 0, 0, 0);
                }
            }
        }
    }
#undef ATTN_CHUNK

    // epilogue: C of PV: col n16 in {d0..d3, den, dst}, rows l = quad*4+r
    float dsr = 0.f;
    #pragma unroll
    for (int i = 0; i < 8; i++) {
        int tl0 = (base_tile + i * 4 + w) * 16;
        if (tl0 >= L) continue;
        #pragma unroll
        for (int r = 0; r < 4; r++) {
            float den = __shfl(acc[i][r], (lane & 48) | 4, 64);
            float rcp = 1.f / den;
            int l = tl0 + quad * 4 + r;
            if (n16 < 4)
                attT[((size_t)b * L + l) * CCH + h * 4 + n16] = (f16)(acc[i][r] * rcp);
            if (n16 == 5) dsr += acc[i][r] * rcp;
        }
    }
    dsr += __shfl_xor(dsr, 16, 64);
    dsr += __shfl_xor(dsr, 32, 64);
    if (n16 == 5 && quad == 0) atomicAdd(dsacc + (size_t)lvl * 128 + (size_t)b * 64 + h, dsr);
}

// ================= o-conv (fp32 out + residual) + finalize ================
__global__ __launch_bounds__(256)
void convo_kernel(const f16* __restrict__ attT, const f16* __restrict__ WF,
                  const float* __restrict__ bo, const float* __restrict__ s0,
                  const float* __restrict__ s1, const float* __restrict__ s2,
                  const float* __restrict__ s3, float* __restrict__ out,
                  const float* __restrict__ dsacc) {
    if (blockIdx.x == 0 && blockIdx.y == 0 && blockIdx.z == 0 && threadIdx.x < 64) {
        int tt = threadIdx.x;
        #pragma unroll
        for (int i = 0; i < 8; i++) {
            float v = dsacc[i * 64 + tt];
            #pragma unroll
            for (int off = 32; off > 0; off >>= 1) v += __shfl_down(v, off);
            if (tt == 0) {
                int lv = i >> 1;
                out[DS_OUT_OFF + i] = v / (float)(HEADS * (4096 >> (2 * lv)));
            }
        }
    }
    int x = blockIdx.x, lvl, xl;
    if (x < 32) { lvl = 0; xl = x; }
    else if (x < 40) { lvl = 1; xl = x - 32; }
    else if (x < 42) { lvl = 2; xl = x - 40; }
    else { lvl = 3; xl = x - 42; }
    int L, M; size_t qo, kvo;
    lvl_tables(lvl, L, M, qo, kvo);
    const float* resid = (lvl == 0) ? s0 : (lvl == 1) ? s1 : (lvl == 2) ? s2 : s3;
    const int ob = blockIdx.y * 64;
    const int n = blockIdx.z;
    const int t = threadIdx.x, w = t >> 6, lane = t & 63;
    const int quad = lane >> 4, n16 = lane & 15;
    const int l0w = xl * 128 + w * 32;
    if (l0w >= L) return;

    const f16* Wf = WF + 3 * 262144 + (size_t)lvl * 65536;
    const float* bias = bo + lvl * 256;

    f32x4 acc[4][2];
    #pragma unroll
    for (int f = 0; f < 4; f++)
        #pragma unroll
        for (int g = 0; g < 2; g++) { acc[f][g][0]=0.f; acc[f][g][1]=0.f; acc[f][g][2]=0.f; acc[f][g][3]=0.f; }

    const f16* xp = attT + qo + ((size_t)n * L + l0w + n16) * CCH + quad * 8;
    const f16* wp = Wf + ((size_t)(ob + n16)) * CCH + quad * 8;

    #pragma unroll
    for (int c0 = 0; c0 < 256; c0 += 32) {
        f16x8 af[4], bf[2];
        #pragma unroll
        for (int f = 0; f < 4; f++) af[f] = *(const f16x8*)(wp + (size_t)f * 16 * CCH + c0);
        #pragma unroll
        for (int g = 0; g < 2; g++) bf[g] = *(const f16x8*)(xp + (size_t)g * 16 * CCH + c0);
        #pragma unroll
        for (int f = 0; f < 4; f++)
            #pragma unroll
            for (int g = 0; g < 2; g++)
                acc[f][g] = __builtin_amdgcn_mfma_f32_16x16x32_f16(af[f], bf[g], acc[f][g], 0, 0, 0);
    }

    #pragma unroll
    for (int f = 0; f < 4; f++) {
        #pragma unroll
        for (int g = 0; g < 2; g++) {
            int lloc = l0w + g * 16 + n16;
            #pragma unroll
            for (int r = 0; r < 4; r++) {
                size_t idx = qo + ((size_t)n * CCH + ob + f * 16 + quad * 4 + r) * (size_t)L + lloc;
                out[idx] = acc[f][g][r] + bias[ob + f * 16 + quad * 4 + r] + resid[idx - qo];
            }
        }
    }
}

extern "C" void kernel_launch(void* const* d_in, const int* in_sizes, int n_in,
                              void* d_out, int out_size, void* d_ws, size_t ws_size,
                              hipStream_t stream) {
    const float* sp[4] = {(const float*)d_in[0], (const float*)d_in[1], (const float*)d_in[2], (const float*)d_in[3]};
    const float* iv[4] = {(const float*)d_in[4], (const float*)d_in[5], (const float*)d_in[6], (const float*)d_in[7]};
    const float* dd[4] = {(const float*)d_in[8], (const float*)d_in[9], (const float*)d_in[10], (const float*)d_in[11]};
    const float* Wq = (const float*)d_in[12];
    const float* bq = (const float*)d_in[13];
    const float* Wk = (const float*)d_in[14];
    const float* bk = (const float*)d_in[15];
    const float* Wv = (const float*)d_in[16];
    const float* bv = (const float*)d_in[17];
    const float* Wo = (const float*)d_in[18];
    const float* bo = (const float*)d_in[19];
    const float* Wdsk = (const float*)d_in[20];
    const float* bdsk = (const float*)d_in[21];
    const float* Wdsv = (const float*)d_in[22];
    const float* bdsv = (const float*)d_in[23];
    const float* gate = (const float*)d_in[24];

    float* ws = (float*)d_ws;
    float* pooled = ws + OFF_POOLED;
    float* dsacc = ws + OFF_DSACC;
    f16* hb = (f16*)((char*)d_ws + 10240);
    f16* qF   = hb + H_Q;
    f16* kF   = hb + H_K;
    f16* vF   = hb + H_V;
    f16* attF = hb + H_ATT;
    f16* spT  = hb + H_SPT;
    f16* ivT  = hb + H_IVT;
    f16* WF   = hb + H_W;
    float* out = (float*)d_out;

    P12 ptrs;
    for (int i = 0; i < 4; i++) { ptrs.a[i] = sp[i]; ptrs.a[4 + i] = iv[i]; ptrs.a[8 + i] = dd[i]; }

    prep_kernel<<<dim3(6976), 256, 0, stream>>>(ptrs, Wq, Wk, Wv, Wo, WF, spT, ivT, pooled, dsacc);

    mid_kernel<<<dim3(1288), 256, 0, stream>>>(spT, ivT, WF, bq, bk, bv, qF, kF, vF,
                                               Wdsk, bdsk, Wdsv, bdsv, gate, pooled);

    attn_all_kernel<<<dim3(12, 64, 2), 256, 0, stream>>>(qF, kF, vF, attF, dsacc);

    convo_kernel<<<dim3(43, 4, 2), 256, 0, stream>>>(attF, WF, bo, sp[0], sp[1], sp[2], sp[3],
                                                     out, dsacc);
}